// Round 11
// baseline (352.316 us; speedup 1.0000x reference)
//
#include <hip/hip_runtime.h>

#define NQ 8
#define DIM 256
#define NLAYER 256

typedef float v2f __attribute__((ext_vector_type(2)));
typedef float v4f __attribute__((ext_vector_type(4)));

// ---------------- Kernel 1: dense per-(m,layer,qubit) gate construction ----
// U = Rz @ Ry @ Rx = [[alpha, beta], [-conj(beta), conj(alpha)]]
// g[((m*256 + i)*8 + q)] = {alpha_r, alpha_i, beta_r, beta_i}
__global__ __launch_bounds__(256) void gates_gen(
    const float* __restrict__ x,   // [M, 256]
    const float* __restrict__ p,   // [256, 8, 3]
    float4* __restrict__ g,
    int total)
{
    const int idx = blockIdx.x * 256 + threadIdx.x;
    if (idx >= total) return;
    const int q = idx & 7;
    const int i = (idx >> 3) & 255;
    const int m = idx >> 11;

    const float he = 0.5f * x[(m << 8) | i];
    const float* __restrict__ pl = p + (i * 8 + q) * 3;
    const float hx = he * pl[0];
    const float hy = he * pl[1];
    const float hz = he * pl[2];
    const float cx = __cosf(hx), sx = __sinf(hx);
    const float cy = __cosf(hy), sy = __sinf(hy);
    const float cz = __cosf(hz), sz = __sinf(hz);
    const float A = cy * cx, B = sy * sx, C = sy * cx, D = cy * sx;
    const float alr = cz * A + sz * B;
    const float ali = cz * B - sz * A;
    const float ber = -(cz * C + sz * D);
    const float bei = sz * C - cz * D;
    g[idx] = make_float4(alr, ali, ber, bei);
}

// ---------------- cross-lane helpers ---------------------------------------
// DPP lane-xor (pure VALU, zero-wait).
template <int CTRL>
__device__ __forceinline__ float dppf(float v) {
    return __builtin_bit_cast(float,
        __builtin_amdgcn_update_dpp(0, __builtin_bit_cast(int, v),
                                    CTRL, 0xf, 0xf, true));
}
// permlane{32,16}_swap self-swap, convention-agnostic combine:
// self-swap yields {X,Y} = {[lo,lo],[hi,hi]} in SOME order; X^Y^own = partner.
__device__ __forceinline__ float plx32(float v) {
    unsigned a = __builtin_bit_cast(unsigned, v);
    unsigned x = a, y = a;
    asm("v_permlane32_swap_b32 %0, %1" : "+v"(x), "+v"(y));
    return __builtin_bit_cast(float, x ^ y ^ a);
}
__device__ __forceinline__ float plx16(float v) {
    unsigned a = __builtin_bit_cast(unsigned, v);
    unsigned x = a, y = a;
    asm("v_permlane16_swap_b32 %0, %1" : "+v"(x), "+v"(y));
    return __builtin_bit_cast(float, x ^ y ^ a);
}
template <int MASK>
__device__ __forceinline__ float lanexor(float v) {
    if constexpr (MASK == 32)     return plx32(v);        // VALU
    else if constexpr (MASK == 16) return plx16(v);       // VALU
    else if constexpr (MASK == 8) return dppf<0x128>(v);  // row_ror:8
    else if constexpr (MASK == 2) return dppf<0x4E>(v);   // quad_perm [2,3,0,1]
    else if constexpr (MASK == 1) return dppf<0xB1>(v);   // quad_perm [1,0,3,2]
    else                          return __shfl_xor(v, MASK, 64);  // mask 4
}

// ---------------- Kernel 2: state evolution, one circuit per wave ----------
// Amplitude idx = lane*4 + j. Qubit q hits bit (7-q): q=0..5 -> lane bits
// (permlane/DPP/shfl), q=6,7 -> slot bits. CNOT chain == Gray gather
// state'[y] = state[y ^ (y>>1)].
// Gates: wave-uniform VMEM dwordx4 (opaque-zero VGPR index defeats s_load
// scalarization -> vmcnt, prefetchable across DS waits), every lane holds all
// 8 gates of the layer in VGPRs -> coefficients are direct FMA operands, no
// readlane/broadcast. Named-scalar ping-pong (no arrays -> no LDS promotion).

#define ROUND(G, Q, MASK) { \
    const float s = sgn[Q]; \
    const float csr = (G).x, csi = s * (G).y; \
    const float cpr = s * (G).z, cpi = (G).w; \
    v2f pr01, pi01, pr23, pi23; \
    pr01.x = lanexor<MASK>(ar01.x); pr01.y = lanexor<MASK>(ar01.y); \
    pi01.x = lanexor<MASK>(ai01.x); pi01.y = lanexor<MASK>(ai01.y); \
    pr23.x = lanexor<MASK>(ar23.x); pr23.y = lanexor<MASK>(ar23.y); \
    pi23.x = lanexor<MASK>(ai23.x); pi23.y = lanexor<MASK>(ai23.y); \
    v2f nar01 = csr * ar01 - csi * ai01 + cpr * pr01 - cpi * pi01; \
    v2f nai01 = csr * ai01 + csi * ar01 + cpr * pi01 + cpi * pr01; \
    v2f nar23 = csr * ar23 - csi * ai23 + cpr * pr23 - cpi * pi23; \
    v2f nai23 = csr * ai23 + csi * ar23 + cpr * pi23 + cpi * pr23; \
    ar01 = nar01; ai01 = nai01; ar23 = nar23; ai23 = nai23; \
}

#define ROUND_Q6(G) { \
    const float alr = (G).x, ali = (G).y, ber = (G).z, bei = (G).w; \
    v2f nar01 = alr * ar01 - ali * ai01 + ber * ar23 - bei * ai23; \
    v2f nai01 = alr * ai01 + ali * ar01 + ber * ai23 + bei * ar23; \
    v2f nar23 = -ber * ar01 - bei * ai01 + alr * ar23 + ali * ai23; \
    v2f nai23 = -ber * ai01 + bei * ar01 + alr * ai23 - ali * ar23; \
    ar01 = nar01; ai01 = nai01; ar23 = nar23; ai23 = nai23; \
}

#define ROUND_Q7(G) { \
    const float alr = (G).x, ali = (G).y, ber = (G).z, bei = (G).w; \
    float xr = ar01.x, xi = ai01.x, yr = ar01.y, yi = ai01.y; \
    ar01.x = alr * xr - ali * xi + ber * yr - bei * yi; \
    ai01.x = alr * xi + ali * xr + ber * yi + bei * yr; \
    ar01.y = -ber * xr - bei * xi + alr * yr + ali * yi; \
    ai01.y = -ber * xi + bei * xr + alr * yi - ali * yr; \
    xr = ar23.x; xi = ai23.x; yr = ar23.y; yi = ai23.y; \
    ar23.x = alr * xr - ali * xi + ber * yr - bei * yi; \
    ai23.x = alr * xi + ali * xr + ber * yi + bei * yr; \
    ar23.y = -ber * xr - bei * xi + alr * yr + ali * yi; \
    ai23.y = -ber * xi + bei * xr + alr * yi - ali * yr; \
}

#define CNOTSTEP() { \
    const float t0r = __shfl(ar01.x, sl, 64), t1r = __shfl(ar01.y, sl, 64); \
    const float t2r = __shfl(ar23.x, sl, 64), t3r = __shfl(ar23.y, sl, 64); \
    const float t0i = __shfl(ai01.x, sl, 64), t1i = __shfl(ai01.y, sl, 64); \
    const float t2i = __shfl(ai23.x, sl, 64), t3i = __shfl(ai23.y, sl, 64); \
    ar01.x = L0 ? t2r : t0r;  ar01.y = L0 ? t3r : t1r; \
    ar23.x = L0 ? t1r : t3r;  ar23.y = L0 ? t0r : t2r; \
    ai01.x = L0 ? t2i : t0i;  ai01.y = L0 ? t3i : t1i; \
    ai23.x = L0 ? t1i : t3i;  ai23.y = L0 ? t0i : t2i; \
}

#define STEP(B) { \
    ROUND(B##0, 0, 32) ROUND(B##1, 1, 16) ROUND(B##2, 2, 8) \
    ROUND(B##3, 3, 4)  ROUND(B##4, 4, 2)  ROUND(B##5, 5, 1) \
    ROUND_Q6(B##6) ROUND_Q7(B##7) CNOTSTEP() \
}

#define LOADL(B, L) { \
    const v4f* gp_ = gv4 + zero + (L) * 8; \
    B##0 = gp_[0]; B##1 = gp_[1]; B##2 = gp_[2]; B##3 = gp_[3]; \
    B##4 = gp_[4]; B##5 = gp_[5]; B##6 = gp_[6]; B##7 = gp_[7]; \
}

__global__ __launch_bounds__(256) void qemb_apply_u(
    const v4f* __restrict__ g,     // [M, 256, 8]
    float* __restrict__ out,       // [M, 256] real parts
    int M)
{
    const int lane = threadIdx.x & 63;
    const int wave = __builtin_amdgcn_readfirstlane((int)(threadIdx.x >> 6));
    const int m = blockIdx.x * 4 + wave;
    if (m >= M) return;

    // Opaque zero in a VGPR: keeps gate loads on the VMEM path (vmcnt),
    // decoupled from the DS shuffles' lgkmcnt.
    int zero; asm("v_mov_b32 %0, 0" : "=v"(zero));

    v2f ar01 = {0.f, 0.f}, ai01 = {0.f, 0.f};
    v2f ar23 = {0.f, 0.f}, ai23 = {0.f, 0.f};
    if (lane == 0) ar01.x = 1.f;

    const v4f* __restrict__ gv4 = g + ((size_t)m << 11);

    float sgn[6];
#pragma unroll
    for (int q = 0; q < 6; ++q) sgn[q] = ((lane >> (5 - q)) & 1) ? -1.f : 1.f;
    const int sl = lane ^ (lane >> 1);   // CNOT source lane
    const bool L0 = lane & 1;

    v4f A0, A1, A2, A3, A4, A5, A6, A7;
    v4f B0, B1, B2, B3, B4, B5, B6, B7;

    LOADL(A, 0);
    for (int i = 0; i < NLAYER; i += 2) {
        LOADL(B, i + 1);                           // prefetch layer i+1
        STEP(A)                                    // compute layer i
        const int n2 = (i + 2 < NLAYER) ? i + 2 : NLAYER - 1;
        LOADL(A, n2);                              // prefetch layer i+2
        STEP(B)                                    // compute layer i+1
    }

    float4* o = reinterpret_cast<float4*>(out + (size_t)m * DIM + lane * 4);
    *o = make_float4(ar01.x, ar01.y, ar23.x, ar23.y);
}

// ---------------- Fallback: monolithic (known-good round-2 kernel) ---------
__global__ __launch_bounds__(256) void qemb_mono(
    const float* __restrict__ x, const float* __restrict__ p,
    float* __restrict__ out, int M)
{
    const int lane = threadIdx.x & 63;
    const int wave = threadIdx.x >> 6;
    const int m = blockIdx.x * 4 + wave;
    if (m >= M) return;
    float ar[4], ai[4];
#pragma unroll
    for (int j = 0; j < 4; ++j) { ar[j] = 0.f; ai[j] = 0.f; }
    if (lane == 0) ar[0] = 1.f;
    const float* __restrict__ xrow = x + (size_t)m * DIM;
    for (int i = 0; i < NLAYER; ++i) {
        const float he = 0.5f * xrow[i];
        const float* __restrict__ pl = p + i * (NQ * 3);
#pragma unroll
        for (int q = 0; q < NQ; ++q) {
            const float hx = he * pl[q * 3 + 0], hy = he * pl[q * 3 + 1], hz = he * pl[q * 3 + 2];
            const float cx = __cosf(hx), sx = __sinf(hx);
            const float cy = __cosf(hy), sy = __sinf(hy);
            const float cz = __cosf(hz), sz = __sinf(hz);
            const float A = cy * cx, B = sy * sx, C = sy * cx, D = cy * sx;
            const float alr = cz * A + sz * B, ali = cz * B - sz * A;
            const float ber = -(cz * C + sz * D), bei = sz * C - cz * D;
            if (q < 6) {
                const int sh = 5 - q;
                const float s = ((lane >> sh) & 1) ? -1.f : 1.f;
                const float csr = alr, csi = s * ali, cpr = s * ber, cpi = bei;
#pragma unroll
                for (int j = 0; j < 4; ++j) {
                    const float pr = __shfl_xor(ar[j], 1 << sh, 64);
                    const float pi = __shfl_xor(ai[j], 1 << sh, 64);
                    const float xr = ar[j], xi = ai[j];
                    ar[j] = csr * xr - csi * xi + cpr * pr - cpi * pi;
                    ai[j] = csr * xi + csi * xr + cpr * pi + cpi * pr;
                }
            } else {
                const int d = (q == 6) ? 2 : 1;
#pragma unroll
                for (int j0 = 0; j0 < 2; ++j0) {
                    const int a = (q == 6) ? j0 : j0 * 2, b = a + d;
                    const float xr = ar[a], xi = ai[a], yr = ar[b], yi = ai[b];
                    ar[a] = alr * xr - ali * xi + ber * yr - bei * yi;
                    ai[a] = alr * xi + ali * xr + ber * yi + bei * yr;
                    ar[b] = -ber * xr - bei * xi + alr * yr + ali * yi;
                    ai[b] = -ber * xi + bei * xr + alr * yi - ali * yr;
                }
            }
        }
        const int srcL = lane ^ (lane >> 1);
        float tr[4], ti[4];
#pragma unroll
        for (int s2 = 0; s2 < 4; ++s2) { tr[s2] = __shfl(ar[s2], srcL, 64); ti[s2] = __shfl(ai[s2], srcL, 64); }
        const int L0 = lane & 1;
        ar[0] = L0 ? tr[2] : tr[0];  ai[0] = L0 ? ti[2] : ti[0];
        ar[1] = L0 ? tr[3] : tr[1];  ai[1] = L0 ? ti[3] : ti[1];
        ar[2] = L0 ? tr[1] : tr[3];  ai[2] = L0 ? ti[1] : ti[3];
        ar[3] = L0 ? tr[0] : tr[2];  ai[3] = L0 ? ti[0] : ti[2];
    }
    float4* o = reinterpret_cast<float4*>(out + (size_t)m * DIM + lane * 4);
    *o = make_float4(ar[0], ar[1], ar[2], ar[3]);
}

extern "C" void kernel_launch(void* const* d_in, const int* in_sizes, int n_in,
                              void* d_out, int out_size, void* d_ws, size_t ws_size,
                              hipStream_t stream) {
    const float* x = (const float*)d_in[0];        // [8,256,256] fp32
    const float* qp = (const float*)d_in[1];       // [256,8,3] fp32
    float* out = (float*)d_out;                    // [8,256,256] fp32 real parts

    const int M = in_sizes[0] / DIM;               // 2048 circuits
    const size_t gates_bytes = (size_t)M * NLAYER * NQ * sizeof(float4);  // 67 MB

    if (ws_size >= gates_bytes) {
        float4* g = (float4*)d_ws;
        const int total = M * NLAYER * NQ;
        gates_gen<<<(total + 255) / 256, 256, 0, stream>>>(x, qp, g, total);
        qemb_apply_u<<<(M + 3) / 4, 256, 0, stream>>>((const v4f*)g, out, M);
    } else {
        qemb_mono<<<(M + 3) / 4, 256, 0, stream>>>(x, qp, out, M);
    }
}

// Round 12
// 311.881 us; speedup vs baseline: 1.1296x; 1.1296x over previous
//
#include <hip/hip_runtime.h>

#define NQ 8
#define DIM 256
#define NLAYER 256

// ---------------- Kernel 1: dense per-(m,layer,qubit) gate construction ----
// U = Rz @ Ry @ Rx = [[alpha, beta], [-conj(beta), conj(alpha)]]
// g[((m*256 + i)*8 + q)] = {alpha_r, alpha_i, beta_r, beta_i}
__global__ __launch_bounds__(256) void gates_gen(
    const float* __restrict__ x,   // [M, 256]
    const float* __restrict__ p,   // [256, 8, 3]
    float4* __restrict__ g,
    int total)
{
    const int idx = blockIdx.x * 256 + threadIdx.x;
    if (idx >= total) return;
    const int q = idx & 7;
    const int i = (idx >> 3) & 255;
    const int m = idx >> 11;

    const float he = 0.5f * x[(m << 8) | i];
    const float* __restrict__ pl = p + (i * 8 + q) * 3;
    const float hx = he * pl[0];
    const float hy = he * pl[1];
    const float hz = he * pl[2];
    const float cx = __cosf(hx), sx = __sinf(hx);
    const float cy = __cosf(hy), sy = __sinf(hy);
    const float cz = __cosf(hz), sz = __sinf(hz);
    const float A = cy * cx, B = sy * sx, C = sy * cx, D = cy * sx;
    const float alr = cz * A + sz * B;
    const float ali = cz * B - sz * A;
    const float ber = -(cz * C + sz * D);
    const float bei = sz * C - cz * D;
    g[idx] = make_float4(alr, ali, ber, bei);
}

typedef float v2f __attribute__((ext_vector_type(2)));

// Uniform broadcast from lane `srclane` (VALU->SGPR, no DS, no lgkmcnt).
__device__ __forceinline__ float bcast(float v, int srclane) {
    return __builtin_bit_cast(float,
        __builtin_amdgcn_readlane(__builtin_bit_cast(int, v), srclane));
}

// Lane-xor via DPP (pure VALU, zero-wait). CTRL: quad_perm or row_ror.
template <int CTRL>
__device__ __forceinline__ float dppf(float v) {
    return __builtin_bit_cast(float,
        __builtin_amdgcn_update_dpp(0, __builtin_bit_cast(int, v),
                                    CTRL, 0xf, 0xf, true));
}

// xor-exchange across lanes: DPP for masks 8/2/1, ds-shuffle otherwise.
template <int MASK>
__device__ __forceinline__ float lanexor(float v) {
    if constexpr (MASK == 8)      return dppf<0x128>(v);  // row_ror:8
    else if constexpr (MASK == 2) return dppf<0x4E>(v);   // quad_perm [2,3,0,1]
    else if constexpr (MASK == 1) return dppf<0xB1>(v);   // quad_perm [1,0,3,2]
    else                          return __shfl_xor(v, MASK, 64);
}

// ---------------- Kernel 2: state evolution, one circuit per wave ----------
// Amplitude idx = lane*4 + j. Qubit q hits bit (7-q): q=0..5 -> lane bits
// (xor-exchange), q=6,7 -> slot bits. CNOT chain == Gray gather
// state'[y] = state[y ^ (y>>1)].
// Gate fetch: lane l loads gate (l&7) of the layer -> ONE coalesced 128B
// global_load_dwordx4 (vmcnt-tracked, divergent address => guaranteed VMEM).
// Double-buffered in two NAMED float4s (no arrays -> no alloca/LDS promotion),
// prefetched one layer ahead; broadcast to SGPRs via v_readlane.
__global__ __launch_bounds__(256) void qemb_apply(
    const float4* __restrict__ g,  // [M, 256, 8]
    float* __restrict__ out,       // [M, 256] real parts
    int M)
{
    const int lane = threadIdx.x & 63;
    const int wave = __builtin_amdgcn_readfirstlane((int)(threadIdx.x >> 6));
    const int m = blockIdx.x * 4 + wave;
    if (m >= M) return;

    v2f ar01 = {0.f, 0.f}, ar23 = {0.f, 0.f};
    v2f ai01 = {0.f, 0.f}, ai23 = {0.f, 0.f};
    if (lane == 0) ar01.x = 1.f;

    const float4* __restrict__ gm = g + ((size_t)m << 11);
    const int gq = lane & 7;             // which gate this lane carries

    float sgn[6];
#pragma unroll
    for (int q = 0; q < 6; ++q) sgn[q] = ((lane >> (5 - q)) & 1) ? -1.f : 1.f;
    const int sl = lane ^ (lane >> 1);   // CNOT source lane
    const bool L0 = lane & 1;

    // One cross-lane round for qubit q (q=0..5), gates broadcast from lane q.
#define ROUND(Q, MASK)                                                        \
    {                                                                         \
        const float g0 = bcast(Gd.x, Q), g1 = bcast(Gd.y, Q);                 \
        const float g2 = bcast(Gd.z, Q), g3 = bcast(Gd.w, Q);                 \
        const float s = sgn[Q];                                               \
        const float csr = g0, csi = s * g1, cpr = s * g2, cpi = g3;           \
        v2f pr01, pi01, pr23, pi23;                                           \
        pr01.x = lanexor<MASK>(ar01.x); pr01.y = lanexor<MASK>(ar01.y);       \
        pi01.x = lanexor<MASK>(ai01.x); pi01.y = lanexor<MASK>(ai01.y);       \
        pr23.x = lanexor<MASK>(ar23.x); pr23.y = lanexor<MASK>(ar23.y);       \
        pi23.x = lanexor<MASK>(ai23.x); pi23.y = lanexor<MASK>(ai23.y);       \
        v2f nar01 = csr * ar01 - csi * ai01 + cpr * pr01 - cpi * pi01;        \
        v2f nai01 = csr * ai01 + csi * ar01 + cpr * pi01 + cpi * pr01;        \
        v2f nar23 = csr * ar23 - csi * ai23 + cpr * pr23 - cpi * pi23;        \
        v2f nai23 = csr * ai23 + csi * ar23 + cpr * pi23 + cpi * pr23;        \
        ar01 = nar01; ai01 = nai01; ar23 = nar23; ai23 = nai23;               \
    }

    auto layer_step = [&](const float4 Gd) {
        ROUND(0, 32) ROUND(1, 16) ROUND(2, 8) ROUND(3, 4) ROUND(4, 2) ROUND(5, 1)
        {   // q = 6: pairs (0,2),(1,3) -> elementwise between packs
            const float alr = bcast(Gd.x, 6), ali = bcast(Gd.y, 6);
            const float ber = bcast(Gd.z, 6), bei = bcast(Gd.w, 6);
            v2f nar01 = alr * ar01 - ali * ai01 + ber * ar23 - bei * ai23;
            v2f nai01 = alr * ai01 + ali * ar01 + ber * ai23 + bei * ar23;
            v2f nar23 = -ber * ar01 - bei * ai01 + alr * ar23 + ali * ai23;
            v2f nai23 = -ber * ai01 + bei * ar01 + alr * ai23 - ali * ar23;
            ar01 = nar01; ai01 = nai01; ar23 = nar23; ai23 = nai23;
        }
        {   // q = 7: pairs (0,1),(2,3) -> within packs
            const float alr = bcast(Gd.x, 7), ali = bcast(Gd.y, 7);
            const float ber = bcast(Gd.z, 7), bei = bcast(Gd.w, 7);
            float xr = ar01.x, xi = ai01.x, yr = ar01.y, yi = ai01.y;
            ar01.x = alr * xr - ali * xi + ber * yr - bei * yi;
            ai01.x = alr * xi + ali * xr + ber * yi + bei * yr;
            ar01.y = -ber * xr - bei * xi + alr * yr + ali * yi;
            ai01.y = -ber * xi + bei * xr + alr * yi - ali * yr;
            xr = ar23.x; xi = ai23.x; yr = ar23.y; yi = ai23.y;
            ar23.x = alr * xr - ali * xi + ber * yr - bei * yi;
            ai23.x = alr * xi + ali * xr + ber * yi + bei * yr;
            ar23.y = -ber * xr - bei * xi + alr * yr + ali * yi;
            ai23.y = -ber * xi + bei * xr + alr * yi - ali * yr;
        }
        // CNOT chain: state'[y] = state[y ^ (y>>1)]
        const float t0r = __shfl(ar01.x, sl, 64), t1r = __shfl(ar01.y, sl, 64);
        const float t2r = __shfl(ar23.x, sl, 64), t3r = __shfl(ar23.y, sl, 64);
        const float t0i = __shfl(ai01.x, sl, 64), t1i = __shfl(ai01.y, sl, 64);
        const float t2i = __shfl(ai23.x, sl, 64), t3i = __shfl(ai23.y, sl, 64);
        ar01.x = L0 ? t2r : t0r;  ar01.y = L0 ? t3r : t1r;
        ar23.x = L0 ? t1r : t3r;  ar23.y = L0 ? t0r : t2r;
        ai01.x = L0 ? t2i : t0i;  ai01.y = L0 ? t3i : t1i;
        ai23.x = L0 ? t1i : t3i;  ai23.y = L0 ? t0i : t2i;
    };

    float4 GA = gm[0 * 8 + gq];   // layer 0 (lane-distributed)
    float4 GB;

    for (int i = 0; i < NLAYER; i += 2) {
        const int n1 = (i + 1 < NLAYER) ? i + 1 : NLAYER - 1;
        GB = gm[n1 * 8 + gq];     // prefetch layer i+1 (in flight over step)
        layer_step(GA);           // compute layer i
        const int n2 = (i + 2 < NLAYER) ? i + 2 : NLAYER - 1;
        GA = gm[n2 * 8 + gq];     // prefetch layer i+2
        layer_step(GB);           // compute layer i+1
    }

    float4* o = reinterpret_cast<float4*>(out + (size_t)m * DIM + lane * 4);
    *o = make_float4(ar01.x, ar01.y, ar23.x, ar23.y);
#undef ROUND
}

// ---------------- Fallback: monolithic (known-good round-2 kernel) ---------
__global__ __launch_bounds__(256) void qemb_mono(
    const float* __restrict__ x, const float* __restrict__ p,
    float* __restrict__ out, int M)
{
    const int lane = threadIdx.x & 63;
    const int wave = threadIdx.x >> 6;
    const int m = blockIdx.x * 4 + wave;
    if (m >= M) return;
    float ar[4], ai[4];
#pragma unroll
    for (int j = 0; j < 4; ++j) { ar[j] = 0.f; ai[j] = 0.f; }
    if (lane == 0) ar[0] = 1.f;
    const float* __restrict__ xrow = x + (size_t)m * DIM;
    for (int i = 0; i < NLAYER; ++i) {
        const float he = 0.5f * xrow[i];
        const float* __restrict__ pl = p + i * (NQ * 3);
#pragma unroll
        for (int q = 0; q < NQ; ++q) {
            const float hx = he * pl[q * 3 + 0], hy = he * pl[q * 3 + 1], hz = he * pl[q * 3 + 2];
            const float cx = __cosf(hx), sx = __sinf(hx);
            const float cy = __cosf(hy), sy = __sinf(hy);
            const float cz = __cosf(hz), sz = __sinf(hz);
            const float A = cy * cx, B = sy * sx, C = sy * cx, D = cy * sx;
            const float alr = cz * A + sz * B, ali = cz * B - sz * A;
            const float ber = -(cz * C + sz * D), bei = sz * C - cz * D;
            if (q < 6) {
                const int sh = 5 - q;
                const float s = ((lane >> sh) & 1) ? -1.f : 1.f;
                const float csr = alr, csi = s * ali, cpr = s * ber, cpi = bei;
#pragma unroll
                for (int j = 0; j < 4; ++j) {
                    const float pr = __shfl_xor(ar[j], 1 << sh, 64);
                    const float pi = __shfl_xor(ai[j], 1 << sh, 64);
                    const float xr = ar[j], xi = ai[j];
                    ar[j] = csr * xr - csi * xi + cpr * pr - cpi * pi;
                    ai[j] = csr * xi + csi * xr + cpr * pi + cpi * pr;
                }
            } else {
                const int d = (q == 6) ? 2 : 1;
#pragma unroll
                for (int j0 = 0; j0 < 2; ++j0) {
                    const int a = (q == 6) ? j0 : j0 * 2, b = a + d;
                    const float xr = ar[a], xi = ai[a], yr = ar[b], yi = ai[b];
                    ar[a] = alr * xr - ali * xi + ber * yr - bei * yi;
                    ai[a] = alr * xi + ali * xr + ber * yi + bei * yr;
                    ar[b] = -ber * xr - bei * xi + alr * yr + ali * yi;
                    ai[b] = -ber * xi + bei * xr + alr * yi - ali * yr;
                }
            }
        }
        const int srcL = lane ^ (lane >> 1);
        float tr[4], ti[4];
#pragma unroll
        for (int s2 = 0; s2 < 4; ++s2) { tr[s2] = __shfl(ar[s2], srcL, 64); ti[s2] = __shfl(ai[s2], srcL, 64); }
        const int L0 = lane & 1;
        ar[0] = L0 ? tr[2] : tr[0];  ai[0] = L0 ? ti[2] : ti[0];
        ar[1] = L0 ? tr[3] : tr[1];  ai[1] = L0 ? ti[3] : ti[1];
        ar[2] = L0 ? tr[1] : tr[3];  ai[2] = L0 ? ti[1] : ti[3];
        ar[3] = L0 ? tr[0] : tr[2];  ai[3] = L0 ? ti[0] : ti[2];
    }
    float4* o = reinterpret_cast<float4*>(out + (size_t)m * DIM + lane * 4);
    *o = make_float4(ar[0], ar[1], ar[2], ar[3]);
}

extern "C" void kernel_launch(void* const* d_in, const int* in_sizes, int n_in,
                              void* d_out, int out_size, void* d_ws, size_t ws_size,
                              hipStream_t stream) {
    const float* x = (const float*)d_in[0];        // [8,256,256] fp32
    const float* qp = (const float*)d_in[1];       // [256,8,3] fp32
    float* out = (float*)d_out;                    // [8,256,256] fp32 real parts

    const int M = in_sizes[0] / DIM;               // 2048 circuits
    const size_t gates_bytes = (size_t)M * NLAYER * NQ * sizeof(float4);  // 67 MB

    if (ws_size >= gates_bytes) {
        float4* g = (float4*)d_ws;
        const int total = M * NLAYER * NQ;
        gates_gen<<<(total + 255) / 256, 256, 0, stream>>>(x, qp, g, total);
        qemb_apply<<<(M + 3) / 4, 256, 0, stream>>>(g, out, M);
    } else {
        qemb_mono<<<(M + 3) / 4, 256, 0, stream>>>(x, qp, out, M);
    }
}